// Round 1
// baseline (653.371 us; speedup 1.0000x reference)
//
#include <hip/hip_runtime.h>
#include <stdint.h>
#include <math.h>

// ---------------------------------------------------------------------------
// RLagnet head: actions = argmax(log_softmax(relu(x@W1+b1)@W2+b2) + gumbel)
// B=131072, IN=512, RED=128, ACT=2. Output int32 [B].
//
// Gumbel noise reproduces jax.random.gumbel(fold_in(key(0),12345),(B,2),f32)
// bit-exactly assuming jax_threefry_partitionable=True (JAX >= 0.4.30):
//   bits[j] = o0^o1 of threefry2x32(folded_key, (0, j)),  j = 2*row + col
// ---------------------------------------------------------------------------

#define BM 128   // rows per block
#define BK 32    // k-chunk
#define IN_CHS 512
#define RED_CHS 128
#define BATCH 131072

__host__ __device__ inline void tf2x32(uint32_t k0, uint32_t k1,
                                       uint32_t x0, uint32_t x1,
                                       uint32_t* o0, uint32_t* o1) {
  uint32_t ks2 = k0 ^ k1 ^ 0x1BD11BDAu;
  x0 += k0; x1 += k1;
#define TFR(r) { x0 += x1; x1 = (x1 << r) | (x1 >> (32 - r)); x1 ^= x0; }
  TFR(13) TFR(15) TFR(26) TFR(6)
  x0 += k1; x1 += ks2 + 1u;
  TFR(17) TFR(29) TFR(16) TFR(24)
  x0 += ks2; x1 += k0 + 2u;
  TFR(13) TFR(15) TFR(26) TFR(6)
  x0 += k0; x1 += k1 + 3u;
  TFR(17) TFR(29) TFR(16) TFR(24)
  x0 += k1; x1 += ks2 + 4u;
  TFR(13) TFR(15) TFR(26) TFR(6)
  x0 += ks2; x1 += k0 + 5u;
#undef TFR
  *o0 = x0; *o1 = x1;
}

__device__ __forceinline__ float gumbel_from_bits(uint32_t bits) {
  // jax uniform(minval=tiny, maxval=1): floats = bitcast((bits>>9)|0x3f800000)-1
  // then floats*(1-tiny)+tiny == floats (fp32) for floats>0, else tiny.
  uint32_t fb = (bits >> 9) | 0x3f800000u;
  float u = __uint_as_float(fb) - 1.0f;
  if (u == 0.0f) u = 1.175494350822287508e-38f;  // FLT_MIN (finfo.tiny)
  // g = -log(-log(u)) with f32 intermediate rounding; each log computed in
  // f64 and rounded -> matches a correctly-rounded f32 log to <=1 ulp.
  float t = -(float)log((double)u);
  return -(float)log((double)t);
}

__global__ __launch_bounds__(256) void rl_head_kernel(
    const float* __restrict__ x, const float* __restrict__ W1,
    const float* __restrict__ b1, const float* __restrict__ W2,
    const float* __restrict__ b2, int* __restrict__ out,
    uint32_t fk0, uint32_t fk1) {
  // smem layout:
  //   phase 1: Xs[BK][BM+1] (4128 f) | Ws[BK][BM] (4096 f)   = 32896 B
  //   phase 2: red[2][BM][17] (4352 f) aliases the same region (post-barrier)
  __shared__ float smem[BK * (BM + 1) + BK * BM];
  float* Xs = smem;                      // Xs[k][r]  -> smem[k*(BM+1)+r]
  float* Ws = smem + BK * (BM + 1);      // Ws[k][c]  -> ...[k*BM+c]
  float* red = smem;                     // red[a][row][t] -> a*2176+row*17+t

  const int tid = threadIdx.x;
  const int tr = tid >> 4;   // 0..15 (row group)
  const int tc = tid & 15;   // 0..15 (col group)
  const int row0 = blockIdx.x * BM;

  float acc[8][8];
#pragma unroll
  for (int i = 0; i < 8; ++i)
#pragma unroll
    for (int j = 0; j < 8; ++j) acc[i][j] = 0.0f;

  for (int kb = 0; kb < IN_CHS; kb += BK) {
    // stage X tile 128x32 (transposed into Xs[k][row]); 1024 float4s
#pragma unroll
    for (int q = 0; q < 4; ++q) {
      int seg = tid + q * 256;
      int r = seg >> 3;        // 0..127
      int c4 = seg & 7;        // 0..7 -> k offset c4*4
      const float4 v =
          *(const float4*)(&x[(size_t)(row0 + r) * IN_CHS + kb + c4 * 4]);
      Xs[(c4 * 4 + 0) * (BM + 1) + r] = v.x;
      Xs[(c4 * 4 + 1) * (BM + 1) + r] = v.y;
      Xs[(c4 * 4 + 2) * (BM + 1) + r] = v.z;
      Xs[(c4 * 4 + 3) * (BM + 1) + r] = v.w;
    }
    // stage W1 tile 32x128; 1024 float4s
#pragma unroll
    for (int q = 0; q < 4; ++q) {
      int seg = tid + q * 256;
      int kk = seg >> 5;       // 0..31
      int c4 = seg & 31;       // col = c4*4
      const float4 v =
          *(const float4*)(&W1[(size_t)(kb + kk) * RED_CHS + c4 * 4]);
      *(float4*)(&Ws[kk * BM + c4 * 4]) = v;
    }
    __syncthreads();
#pragma unroll 4
    for (int k = 0; k < BK; ++k) {
      float a[8], b[8];
#pragma unroll
      for (int i = 0; i < 8; ++i) a[i] = Xs[k * (BM + 1) + tr * 8 + i];
#pragma unroll
      for (int j = 0; j < 8; ++j) b[j] = Ws[k * BM + tc * 8 + j];
#pragma unroll
      for (int i = 0; i < 8; ++i)
#pragma unroll
        for (int j = 0; j < 8; ++j) acc[i][j] = fmaf(a[i], b[j], acc[i][j]);
    }
    __syncthreads();
  }

  // epilogue: bias + relu, then partial layer-2 dots over this thread's 8 cols
  float p0[8], p1[8];
#pragma unroll
  for (int i = 0; i < 8; ++i) { p0[i] = 0.0f; p1[i] = 0.0f; }
#pragma unroll
  for (int j = 0; j < 8; ++j) {
    int c = tc * 8 + j;
    float bb = b1[c];
    float w20 = W2[c * 2 + 0];
    float w21 = W2[c * 2 + 1];
#pragma unroll
    for (int i = 0; i < 8; ++i) {
      float h = acc[i][j] + bb;
      h = h > 0.0f ? h : 0.0f;
      p0[i] = fmaf(h, w20, p0[i]);
      p1[i] = fmaf(h, w21, p1[i]);
    }
  }
  // red region aliases Xs/Ws; safe after the loop-final __syncthreads()
#pragma unroll
  for (int i = 0; i < 8; ++i) {
    red[0 * 2176 + (tr * 8 + i) * 17 + tc] = p0[i];
    red[1 * 2176 + (tr * 8 + i) * 17 + tc] = p1[i];
  }
  __syncthreads();

  if (tid < BM) {
    float l0 = b2[0], l1 = b2[1];
#pragma unroll
    for (int t = 0; t < 16; ++t) {
      l0 += red[0 * 2176 + tid * 17 + t];
      l1 += red[1 * 2176 + tid * 17 + t];
    }
    // log_softmax exactly as jax.nn.log_softmax (f32 pipeline)
    float m = fmaxf(l0, l1);
    float s0 = l0 - m, s1 = l1 - m;
    float e0 = (float)exp((double)s0);
    float e1 = (float)exp((double)s1);
    float lse = (float)log((double)(e0 + e1));
    float lp0 = s0 - lse, lp1 = s1 - lse;
    // gumbel: partitionable threefry, flat index j = 2*row + col
    int gr = row0 + tid;
    uint32_t a0, a1, c0, c1;
    tf2x32(fk0, fk1, 0u, (uint32_t)(2 * gr), &a0, &a1);
    tf2x32(fk0, fk1, 0u, (uint32_t)(2 * gr + 1), &c0, &c1);
    float g0 = gumbel_from_bits(a0 ^ a1);
    float g1 = gumbel_from_bits(c0 ^ c1);
    float v0 = lp0 + g0;
    float v1 = lp1 + g1;
    out[gr] = (v1 > v0) ? 1 : 0;  // jnp.argmax: first max wins on tie
  }
}

extern "C" void kernel_launch(void* const* d_in, const int* in_sizes, int n_in,
                              void* d_out, int out_size, void* d_ws,
                              size_t ws_size, hipStream_t stream) {
  (void)in_sizes; (void)n_in; (void)d_ws; (void)ws_size; (void)out_size;
  const float* x = (const float*)d_in[0];
  const float* W1 = (const float*)d_in[1];
  const float* b1 = (const float*)d_in[2];
  const float* W2 = (const float*)d_in[3];
  const float* b2 = (const float*)d_in[4];
  int* out = (int*)d_out;

  // folded key = threefry2x32(key=(0,0), counts=(0,12345))  [fold_in(key(0),12345)]
  uint32_t fk0, fk1;
  tf2x32(0u, 0u, 0u, 12345u, &fk0, &fk1);

  dim3 grid(BATCH / BM);  // 1024 blocks
  rl_head_kernel<<<grid, 256, 0, stream>>>(x, W1, b1, W2, b2, out, fk0, fk1);
}

// Round 2
// 370.703 us; speedup vs baseline: 1.7625x; 1.7625x over previous
//
#include <hip/hip_runtime.h>
#include <stdint.h>
#include <math.h>

// ---------------------------------------------------------------------------
// actions = argmax(log_softmax(relu(x@W1+b1)@W2+b2) + gumbel(fold_in(key0,12345)))
// B=131072, IN=512, RED=128, ACT=2. Output int32 [B].
//
// GEMM via bf16 MFMA with hi/lo split (4 cross products) -> ~1e-6 logit error,
// same order as fp32 reassociation noise (round-1 passed absmax 0).
// Sampling numerics identical to round-1 (bit-exact partitionable threefry).
// ---------------------------------------------------------------------------

#define BM 128
#define BK 32
#define LDK 40   // LDS row stride in bf16 units (80 B = 20 banks -> uniform)
#define IN_CHS 512
#define RED_CHS 128
#define BATCH 131072

typedef __attribute__((ext_vector_type(8))) short bf16x8;
typedef __attribute__((ext_vector_type(4))) float f32x4;

__host__ __device__ inline void tf2x32(uint32_t k0, uint32_t k1,
                                       uint32_t x0, uint32_t x1,
                                       uint32_t* o0, uint32_t* o1) {
  uint32_t ks2 = k0 ^ k1 ^ 0x1BD11BDAu;
  x0 += k0; x1 += k1;
#define TFR(r) { x0 += x1; x1 = (x1 << r) | (x1 >> (32 - r)); x1 ^= x0; }
  TFR(13) TFR(15) TFR(26) TFR(6)
  x0 += k1; x1 += ks2 + 1u;
  TFR(17) TFR(29) TFR(16) TFR(24)
  x0 += ks2; x1 += k0 + 2u;
  TFR(13) TFR(15) TFR(26) TFR(6)
  x0 += k0; x1 += k1 + 3u;
  TFR(17) TFR(29) TFR(16) TFR(24)
  x0 += k1; x1 += ks2 + 4u;
  TFR(13) TFR(15) TFR(26) TFR(6)
  x0 += ks2; x1 += k0 + 5u;
#undef TFR
  *o0 = x0; *o1 = x1;
}

__device__ __forceinline__ float gumbel_from_bits(uint32_t bits) {
  uint32_t fb = (bits >> 9) | 0x3f800000u;
  float u = __uint_as_float(fb) - 1.0f;
  if (u == 0.0f) u = 1.175494350822287508e-38f;  // FLT_MIN
  float t = -(float)log((double)u);
  return -(float)log((double)t);
}

__device__ __forceinline__ unsigned short f2bf(float f) {
  uint32_t u = __float_as_uint(f);
  return (unsigned short)((u + 0x7fffu + ((u >> 16) & 1u)) >> 16);  // RNE
}
__device__ __forceinline__ float bf2f(unsigned short h) {
  return __uint_as_float(((uint32_t)h) << 16);
}

__global__ __launch_bounds__(256) void rl_head_mfma(
    const float* __restrict__ x, const float* __restrict__ W1,
    const float* __restrict__ b1, const float* __restrict__ W2,
    const float* __restrict__ b2, int* __restrict__ out,
    uint32_t fk0, uint32_t fk1) {
  // LDS: A_hi | A_lo | B_hi | B_lo, each BM x LDK bf16 (10240 B) = 40960 B.
  // Epilogue reduction (17408 B) aliases the same region after final barrier.
  __shared__ __align__(16) char smem[4 * BM * LDK * 2];
  unsigned short* Ah = (unsigned short*)smem;
  unsigned short* Al = Ah + BM * LDK;
  unsigned short* Bh = Al + BM * LDK;
  // Bl = Bh + BM*LDK (accessed by offset)
  float* red = (float*)smem;

  const int tid = threadIdx.x;
  const int lane = tid & 63;
  const int w = tid >> 6;        // wave 0..3 -> rows [w*32, w*32+32)
  const int ln = lane & 15;
  const int quad = lane >> 4;
  const int row0 = blockIdx.x * BM;

  // staging assignments
  const int ar = tid >> 3;         // 0..31
  const int ak = (tid & 7) * 4;    // k offset 0..28
  const int bc = tid & 127;        // W1 col
  const int bk0 = (tid >> 7) * 16; // W1 k half

  f32x4 acc[2][8];
#pragma unroll
  for (int i = 0; i < 2; ++i)
#pragma unroll
    for (int j = 0; j < 8; ++j) acc[i][j] = (f32x4)(0.0f);

  for (int kb = 0; kb < IN_CHS; kb += BK) {
    // ---- global loads ----
    float4 av[4];
#pragma unroll
    for (int q = 0; q < 4; ++q)
      av[q] = *(const float4*)(&x[(size_t)(row0 + q * 32 + ar) * IN_CHS + kb + ak]);
    float bv[16];
#pragma unroll
    for (int i = 0; i < 16; ++i)
      bv[i] = W1[(size_t)(kb + bk0 + i) * RED_CHS + bc];

    // ---- convert + LDS stage: A ----
#pragma unroll
    for (int q = 0; q < 4; ++q) {
      const int r = q * 32 + ar;
      float f[4] = {av[q].x, av[q].y, av[q].z, av[q].w};
      ushort4 h4, l4;
      unsigned short* hp = (unsigned short*)&h4;
      unsigned short* lp = (unsigned short*)&l4;
#pragma unroll
      for (int c = 0; c < 4; ++c) {
        unsigned short h = f2bf(f[c]);
        hp[c] = h;
        lp[c] = f2bf(f[c] - bf2f(h));
      }
      *(ushort4*)(&Ah[r * LDK + ak]) = h4;
      *(ushort4*)(&Al[r * LDK + ak]) = l4;
    }
    // ---- convert + LDS stage: B (W1[k][c] -> Bh[c][k]) ----
    {
      ushort4 h4[4], l4[4];
#pragma unroll
      for (int g = 0; g < 4; ++g) {
        unsigned short* hp = (unsigned short*)&h4[g];
        unsigned short* lp = (unsigned short*)&l4[g];
#pragma unroll
        for (int c = 0; c < 4; ++c) {
          float f = bv[g * 4 + c];
          unsigned short h = f2bf(f);
          hp[c] = h;
          lp[c] = f2bf(f - bf2f(h));
        }
      }
#pragma unroll
      for (int g = 0; g < 4; ++g) {
        *(ushort4*)(&Bh[bc * LDK + bk0 + g * 4]) = h4[g];
        *(ushort4*)(&Bh[BM * LDK + bc * LDK + bk0 + g * 4]) = l4[g];
      }
    }
    __syncthreads();

    // ---- MFMA: frag m = lane&15, k = quad*8+j ----
    const unsigned short* ap = &Ah[(w * 32 + ln) * LDK + quad * 8];
    bf16x8 ah0 = *(const bf16x8*)ap;
    bf16x8 ah1 = *(const bf16x8*)(ap + 16 * LDK);
    bf16x8 al0 = *(const bf16x8*)(ap + BM * LDK);
    bf16x8 al1 = *(const bf16x8*)(ap + BM * LDK + 16 * LDK);
#pragma unroll
    for (int ct = 0; ct < 8; ++ct) {
      const unsigned short* bp = &Bh[(ct * 16 + ln) * LDK + quad * 8];
      bf16x8 bh = *(const bf16x8*)bp;
      bf16x8 bl = *(const bf16x8*)(bp + BM * LDK);
      acc[0][ct] = __builtin_amdgcn_mfma_f32_16x16x32_bf16(ah0, bh, acc[0][ct], 0, 0, 0);
      acc[0][ct] = __builtin_amdgcn_mfma_f32_16x16x32_bf16(ah0, bl, acc[0][ct], 0, 0, 0);
      acc[0][ct] = __builtin_amdgcn_mfma_f32_16x16x32_bf16(al0, bh, acc[0][ct], 0, 0, 0);
      acc[0][ct] = __builtin_amdgcn_mfma_f32_16x16x32_bf16(al0, bl, acc[0][ct], 0, 0, 0);
      acc[1][ct] = __builtin_amdgcn_mfma_f32_16x16x32_bf16(ah1, bh, acc[1][ct], 0, 0, 0);
      acc[1][ct] = __builtin_amdgcn_mfma_f32_16x16x32_bf16(ah1, bl, acc[1][ct], 0, 0, 0);
      acc[1][ct] = __builtin_amdgcn_mfma_f32_16x16x32_bf16(al1, bh, acc[1][ct], 0, 0, 0);
      acc[1][ct] = __builtin_amdgcn_mfma_f32_16x16x32_bf16(al1, bl, acc[1][ct], 0, 0, 0);
    }
    __syncthreads();
  }

  // ---- epilogue: bias+relu, layer-2 partials per lane ----
  // C layout: col = ct*16 + ln, row = w*32 + rt*16 + quad*4 + reg
  float part[8][2];
#pragma unroll
  for (int s = 0; s < 8; ++s) { part[s][0] = 0.0f; part[s][1] = 0.0f; }
#pragma unroll
  for (int ct = 0; ct < 8; ++ct) {
    const int col = ct * 16 + ln;
    const float bb = b1[col];
    const float w20 = W2[col * 2 + 0];
    const float w21 = W2[col * 2 + 1];
#pragma unroll
    for (int rt = 0; rt < 2; ++rt)
#pragma unroll
      for (int reg = 0; reg < 4; ++reg) {
        float h = acc[rt][ct][reg] + bb;
        h = h > 0.0f ? h : 0.0f;
        part[rt * 4 + reg][0] = fmaf(h, w20, part[rt * 4 + reg][0]);
        part[rt * 4 + reg][1] = fmaf(h, w21, part[rt * 4 + reg][1]);
      }
  }
  // red[row][t][c16] with stride 17 floats; aliases tile LDS (post-barrier)
#pragma unroll
  for (int rt = 0; rt < 2; ++rt)
#pragma unroll
    for (int reg = 0; reg < 4; ++reg) {
      const int row = w * 32 + rt * 16 + quad * 4 + reg;
      red[(row * 2 + 0) * 17 + ln] = part[rt * 4 + reg][0];
      red[(row * 2 + 1) * 17 + ln] = part[rt * 4 + reg][1];
    }
  __syncthreads();

  if (tid < BM) {
    const int row = tid;
    float l0 = b2[0], l1 = b2[1];
#pragma unroll
    for (int c = 0; c < 16; ++c) {
      l0 += red[(row * 2 + 0) * 17 + c];
      l1 += red[(row * 2 + 1) * 17 + c];
    }
    float m = fmaxf(l0, l1);
    float s0 = l0 - m, s1 = l1 - m;
    float e0 = (float)exp((double)s0);
    float e1 = (float)exp((double)s1);
    float lse = (float)log((double)(e0 + e1));
    float lp0 = s0 - lse, lp1 = s1 - lse;
    const int gr = row0 + row;
    uint32_t a0, a1, c0, c1;
    tf2x32(fk0, fk1, 0u, (uint32_t)(2 * gr), &a0, &a1);
    tf2x32(fk0, fk1, 0u, (uint32_t)(2 * gr + 1), &c0, &c1);
    float g0 = gumbel_from_bits(a0 ^ a1);
    float g1 = gumbel_from_bits(c0 ^ c1);
    out[gr] = ((lp1 + g1) > (lp0 + g0)) ? 1 : 0;
  }
}

extern "C" void kernel_launch(void* const* d_in, const int* in_sizes, int n_in,
                              void* d_out, int out_size, void* d_ws,
                              size_t ws_size, hipStream_t stream) {
  (void)in_sizes; (void)n_in; (void)d_ws; (void)ws_size; (void)out_size;
  const float* x = (const float*)d_in[0];
  const float* W1 = (const float*)d_in[1];
  const float* b1 = (const float*)d_in[2];
  const float* W2 = (const float*)d_in[3];
  const float* b2 = (const float*)d_in[4];
  int* out = (int*)d_out;

  uint32_t fk0, fk1;
  tf2x32(0u, 0u, 0u, 12345u, &fk0, &fk1);

  dim3 grid(BATCH / BM);  // 1024 blocks
  rl_head_mfma<<<grid, 256, 0, stream>>>(x, W1, b1, W2, b2, out, fk0, fk1);
}